// Round 2
// baseline (116.487 us; speedup 1.0000x reference)
//
#include <hip/hip_runtime.h>
#include <hip/hip_fp16.h>

// SuppLayer: out[b,c] = exp( sum_s x[b, cm[c,s]] * w[c,s] )
// B=4096, NCLASS=1000, NSUPP=64, NCHUNK=4096.
//
// R11: inter-block pipelining instead of intra-block (R10's T14 overlap was
// defeated by vmcnt ordering: cm/w prefetches queued behind the 32 hv loads,
// so the first cm-wait drained the whole hi-half HBM stream).
//  - BT=8 rows/block, LDS tile 64 KB -> 2 blocks/CU (512 blocks total).
//    Block A's staging overlaps block B's gather with no vmcnt entanglement.
//  - 64-VGPR budget (__launch_bounds__(1024,8)) to actually get 32 waves/CU.
//    Lean body: no cm/w ILP pipeline (8 waves/SIMD TLP hides L2 latency),
//    no register-staged half, no pointer arrays (scratch trap, rule #20).
//  - Slot = 16 B = 8 rows fp16 at tile4[idx]; read quad = idx&7 (all 8 quads
//    in play). Pre-pass counting-sorts each class's pairs by (idx-c)&7 and
//    writes [sg][class]-transposed cmT/wT (coalesced int4/float4 loads).

constexpr int B_       = 4096;
constexpr int NCLASS_  = 1000;
constexpr int NSUPP_   = 64;
constexpr int NCHUNK_  = 4096;
constexpr int BT       = 8;      // batch rows per block
constexpr int THREADS_ = 1024;
constexpr int SG_      = NSUPP_ / 4;            // 16 int4/float4 groups
constexpr size_t CMT_BYTES = (size_t)SG_ * NCLASS_ * 16;   // 256 KB
constexpr size_t WS_NEEDED = 2 * CMT_BYTES;                // 512 KB

// ---- pre-pass: one wave per class. Sort 64 (idx,w) by key=(idx-c)&7 and
// write to [sg][class] transposed layout. All-register rank computation. ----
__global__ __launch_bounds__(256)
void build_cw_kernel(const int*   __restrict__ cm,
                     const float* __restrict__ w,
                     int*         __restrict__ cmT,
                     float*       __restrict__ wT)
{
    const int t    = threadIdx.x;
    const int c    = blockIdx.x * 4 + (t >> 6);   // 4 classes per block
    const int lane = t & 63;
    if (c >= NCLASS_) return;                      // grid=250 -> never taken

    const int   idx = cm[c * NSUPP_ + lane];
    const float wv  = w [c * NSUPP_ + lane];
    const int   key = (idx - c) & 7;               // read quad = idx&7

    // stable rank of this element in sorted-by-key order
    const unsigned long long below = ((unsigned long long)1 << lane) - 1ull;
    int j = 0;
    #pragma unroll
    for (int r = 0; r < 8; ++r) {
        const unsigned long long m = __ballot(key == r);
        if (key > r)  j += __popcll(m);
        if (key == r) j += __popcll(m & below);
    }

    const int dst = ((j >> 2) * NCLASS_ + c) * 4 + (j & 3);
    cmT[dst] = idx;
    wT [dst] = wv;
}

template <bool USET>
__global__ __launch_bounds__(THREADS_, 8)
void supp_gather_kernel(const float* __restrict__ x,
                        const float* __restrict__ wSupp,
                        const int*   __restrict__ cmap,
                        const float4* __restrict__ wT,
                        const int4*   __restrict__ cmT,
                        float*       __restrict__ out)
{
    // slot idx = 16 B = 8 rows as half2 pairs (rows 2k,2k+1)  -> 64 KB
    __shared__ __align__(16) __half2 tile[NCHUNK_ * 4];

    const int t  = threadIdx.x;
    const int rb = blockIdx.x * BT;   // first batch row of this tile

    // ---- stage: 8 rows of x -> fp16, transposed into LDS ----
    // thread t owns cols col = t + 1024p; consecutive lanes write
    // consecutive 16B slots -> all 8 quads cycle, conflict-free.
    #pragma unroll
    for (int p = 0; p < NCHUNK_ / THREADS_; ++p) {
        const int col = t + THREADS_ * p;
        float v[BT];
        #pragma unroll
        for (int bi = 0; bi < BT; ++bi)
            v[bi] = x[(size_t)(rb + bi) * NCHUNK_ + col];
        __half2 h[BT / 2];
        #pragma unroll
        for (int k = 0; k < BT / 2; ++k)
            h[k] = __floats2half2_rn(v[2 * k], v[2 * k + 1]);
        *reinterpret_cast<float4*>(&tile[(size_t)col * 4]) =
            *reinterpret_cast<const float4*>(&h[0]);
    }
    __syncthreads();

    // ---- gather: one class per thread, no ILP pipeline (TLP covers L2) ----
    if (t < NCLASS_) {
        const int c = t;
        const float4* tile4 = reinterpret_cast<const float4*>(tile);
        float acc[BT];
        #pragma unroll
        for (int bi = 0; bi < BT; ++bi) acc[bi] = 0.f;

        for (int sg = 0; sg < SG_; ++sg) {
            int4   ci;
            float4 wf;
            if constexpr (USET) {
                ci = cmT[sg * NCLASS_ + c];
                wf = wT [sg * NCLASS_ + c];
            } else {
                ci = reinterpret_cast<const int4*>(cmap + c * NSUPP_)[sg];
                wf = reinterpret_cast<const float4*>(wSupp + c * NSUPP_)[sg];
            }

            // 4 independent ds_read_b128, explicitly unrolled uses
            const float4 d0 = tile4[ci.x];
            const float4 d1 = tile4[ci.y];
            const float4 d2 = tile4[ci.z];
            const float4 d3 = tile4[ci.w];

            const __half2* h0 = reinterpret_cast<const __half2*>(&d0);
            const __half2* h1 = reinterpret_cast<const __half2*>(&d1);
            const __half2* h2 = reinterpret_cast<const __half2*>(&d2);
            const __half2* h3 = reinterpret_cast<const __half2*>(&d3);
            #pragma unroll
            for (int k = 0; k < 4; ++k) {
                float2 f;
                f = __half22float2(h0[k]);
                acc[2 * k]     = fmaf(f.x, wf.x, acc[2 * k]);
                acc[2 * k + 1] = fmaf(f.y, wf.x, acc[2 * k + 1]);
                f = __half22float2(h1[k]);
                acc[2 * k]     = fmaf(f.x, wf.y, acc[2 * k]);
                acc[2 * k + 1] = fmaf(f.y, wf.y, acc[2 * k + 1]);
                f = __half22float2(h2[k]);
                acc[2 * k]     = fmaf(f.x, wf.z, acc[2 * k]);
                acc[2 * k + 1] = fmaf(f.y, wf.z, acc[2 * k + 1]);
                f = __half22float2(h3[k]);
                acc[2 * k]     = fmaf(f.x, wf.w, acc[2 * k]);
                acc[2 * k + 1] = fmaf(f.y, wf.w, acc[2 * k + 1]);
            }
        }
        #pragma unroll
        for (int bi = 0; bi < BT; ++bi)
            out[(size_t)(rb + bi) * NCLASS_ + c] = __expf(acc[bi]);
    }
}

extern "C" void kernel_launch(void* const* d_in, const int* in_sizes, int n_in,
                              void* d_out, int out_size, void* d_ws, size_t ws_size,
                              hipStream_t stream) {
    const float* x  = (const float*)d_in[0];   // (B, NCHUNK) fp32
    const float* w  = (const float*)d_in[1];   // (NCLASS, NSUPP) fp32
    const int*   cm = (const int*)d_in[2];     // (NCLASS, NSUPP) int32
    float*       o  = (float*)d_out;           // (B, NCLASS) fp32

    int*   cmT = (int*)d_ws;
    float* wT  = (float*)((char*)d_ws + CMT_BYTES);

    const dim3 grid(B_ / BT);                  // 512 blocks, 2 per CU
    if (ws_size >= WS_NEEDED) {
        build_cw_kernel<<<dim3((NCLASS_ + 3) / 4), dim3(256), 0, stream>>>(
            cm, w, cmT, wT);
        supp_gather_kernel<true><<<grid, dim3(THREADS_), 0, stream>>>(
            x, w, cm, (const float4*)wT, (const int4*)cmT, o);
    } else {
        supp_gather_kernel<false><<<grid, dim3(THREADS_), 0, stream>>>(
            x, w, cm, (const float4*)wT, (const int4*)cmT, o);
    }
}